// Round 12
// baseline (85.416 us; speedup 1.0000x reference)
//
#include <hip/hip_runtime.h>

#define D_MODEL 1024
#define L_SEQ   2048
#define N_BATCH 8
#define N_TOK   (N_BATCH * L_SEQ)   // 16384
#define N_REGS  8
#define D_REG   32
#define LN_EPS  1e-5f

// scan geometry: 16-step half-chunks
#define HSTEP   16
#define N_HALF  128                 // per (b,r): 2048 / 16

// k_lnmfma LDS geometry (all offsets in dwords)
#define ASTR    36                  // row stride: 72 bf16 (64 k + 8 pad) = 36 dwords
#define ABUF    (64 * ASTR)         // 2304 dwords per fragment array
#define BUFSZ   (4 * ABUF)          // Ah,Al,Bh,Bl = 9216 dwords per buffer
#define OFF_AH  0
#define OFF_AL  ABUF
#define OFF_BH  (2 * ABUF)
#define OFF_BL  (3 * ABUF)
#define OFF_SB  (2 * BUFSZ)         // 18432
#define SBSTR   68
#define OFF_PH  (OFF_SB + 64 * SBSTR)   // 22784
#define OFF_PS  (OFF_PH + 64 * 17)      // 23872
#define LDS_DW  (OFF_PS + 64 * 17)      // 24960 dwords = 99840 B

typedef short short8v __attribute__((ext_vector_type(8)));
typedef short short4v __attribute__((ext_vector_type(4)));
typedef float float4v __attribute__((ext_vector_type(4)));

__device__ __forceinline__ float wred(float v) {
    #pragma unroll
    for (int off = 32; off > 0; off >>= 1) v += __shfl_xor(v, off, 64);
    return v;
}

__device__ __forceinline__ float sigmoidf(float z) {
    return 1.f / (1.f + expf(-z));
}

__device__ __forceinline__ unsigned short f2bf(float f) {
    unsigned u = __float_as_uint(f);
    return (unsigned short)((u + 0x7FFFu + ((u >> 16) & 1u)) >> 16);
}
__device__ __forceinline__ float bf2f(unsigned short h) {
    return __uint_as_float(((unsigned)h) << 16);
}

// ---------------------------------------------------------------------------
// Prep v2: fold ln_w into the 49 projection rows, store TRANSPOSED bf16 hi/lo
// weight matrices Wbh/Wbl [64 f][1024 k] (f>=49 zero), plus
// c1[f] = sum_k W[f,k]*ln_w[k], c2[f] = sum_k W[f,k]*ln_b[k] + bias[f].
// Feature order: 0..7 Wrq, 8..15 Wwq, 16 Wwg, 17..48 Wwv. Grid 64 x 256.
// ---------------------------------------------------------------------------
__global__ __launch_bounds__(256) void k_prep2(
    const float* __restrict__ ln_w, const float* __restrict__ ln_b,
    const float* __restrict__ Wrq,  const float* __restrict__ brq,
    const float* __restrict__ Wwq,  const float* __restrict__ bwq,
    const float* __restrict__ Wwv,  const float* __restrict__ bwv,
    const float* __restrict__ Wwg,  const float* __restrict__ bwg,
    unsigned short* __restrict__ Wbh, unsigned short* __restrict__ Wbl,
    float* __restrict__ c1, float* __restrict__ c2)
{
    const int f = blockIdx.x;            // 0..63

    const float* wrow = nullptr; float bias = 0.f;
    if (f < 8)        { wrow = Wrq + f * D_MODEL;        bias = brq[f]; }
    else if (f < 16)  { wrow = Wwq + (f - 8) * D_MODEL;  bias = bwq[f - 8]; }
    else if (f == 16) { wrow = Wwg;                      bias = bwg[0]; }
    else if (f < 49)  { wrow = Wwv + (f - 17) * D_MODEL; bias = bwv[f - 17]; }

    float p1 = 0.f, p2 = 0.f;
    #pragma unroll
    for (int j = 0; j < 4; ++j) {
        const int k = j * 256 + threadIdx.x;
        float w  = wrow ? wrow[k] : 0.f;
        float wp = w * ln_w[k];
        unsigned short h = f2bf(wp);
        unsigned short l = f2bf(wp - bf2f(h));
        Wbh[(size_t)f * D_MODEL + k] = h;
        Wbl[(size_t)f * D_MODEL + k] = l;
        p1 += wp;
        p2 = fmaf(w, ln_b[k], p2);
    }
    p1 = wred(p1); p2 = wred(p2);

    __shared__ float r1[4], r2[4];
    const int l = threadIdx.x & 63, w = threadIdx.x >> 6;
    if (l == 0) { r1[w] = p1; r2[w] = p2; }
    __syncthreads();
    if (threadIdx.x == 0) {
        c1[f] = r1[0] + r1[1] + r1[2] + r1[3];
        c2[f] = r2[0] + r2[1] + r2[2] + r2[3] + bias;
    }
}

// ---------------------------------------------------------------------------
// Convert float4 -> bf16 hi/lo pairs, write to A buffers, accumulate stats.
// ---------------------------------------------------------------------------
__device__ __forceinline__ void cvt_write_a(
    float* lds, int wb, int stok, int skq, float4 v, float& ssum, float& ssq)
{
    unsigned short h0 = f2bf(v.x), h1 = f2bf(v.y), h2 = f2bf(v.z), h3 = f2bf(v.w);
    short4v hv, lv;
    hv[0] = (short)h0; hv[1] = (short)h1; hv[2] = (short)h2; hv[3] = (short)h3;
    lv[0] = (short)f2bf(v.x - bf2f(h0));
    lv[1] = (short)f2bf(v.y - bf2f(h1));
    lv[2] = (short)f2bf(v.z - bf2f(h2));
    lv[3] = (short)f2bf(v.w - bf2f(h3));
    *reinterpret_cast<short4v*>(lds + wb + OFF_AH + stok * ASTR + skq * 2) = hv;
    *reinterpret_cast<short4v*>(lds + wb + OFF_AL + stok * ASTR + skq * 2) = lv;
    ssum += v.x + v.y + v.z + v.w;
    ssq = fmaf(v.x, v.x, fmaf(v.y, v.y, fmaf(v.z, v.z, fmaf(v.w, v.w, ssq))));
}

// ---------------------------------------------------------------------------
// Kernel A v5: MFMA projection. Block = 64 tokens x 64 features (49 used),
// 1024 thr = 16 waves = 4 token-tiles x 4 feature-tiles of 16x16.
// K = 1024 in 16 chunks of 64, double-buffered LDS; x converted to bf16
// hi/lo on the fly (3-term split GEMM, fp32 accum); LN stats in fp32 on raw x.
// Epilogue identical math to lnproj3. Dynamic LDS = 99840 B.
// ---------------------------------------------------------------------------
__global__ __launch_bounds__(1024) void k_lnmfma(
    const float* __restrict__ x,
    const uint4* __restrict__ Wbh, const uint4* __restrict__ Wbl,
    const float* __restrict__ c1, const float* __restrict__ c2,
    float* __restrict__ rw_o, float* __restrict__ us_o, float* __restrict__ wv_o)
{
    extern __shared__ float lds[];

    const int tid  = threadIdx.x;
    const int lane = tid & 63;
    const int wv   = tid >> 6;          // 0..15
    const int tt   = wv >> 2;           // token tile
    const int ft   = wv & 3;            // feature tile
    const int tok0 = blockIdx.x * 64;

    // staging roles: A: (stok, skq) float4 of 4 k's; B: (sf, sub) one uint4
    const int stok = tid >> 4;          // 0..63 (token row / feature row)
    const int skq  = tid & 15;
    const float4* xg4 = reinterpret_cast<const float4*>(x) + (size_t)(tok0 + stok) * 256;
    const uint4*  wsrc = (skq < 8 ? Wbh : Wbl) + (size_t)stok * 128;
    const int     wkq  = skq & 7;
    const int     wdst = (skq < 8 ? OFF_BH : OFF_BL) + stok * ASTR + wkq * 4;

    float ssum = 0.f, ssq = 0.f;
    float4 xg = xg4[skq];
    uint4  bg = wsrc[wkq];

    cvt_write_a(lds, 0, stok, skq, xg, ssum, ssq);
    *reinterpret_cast<uint4*>(lds + wdst) = bg;
    __syncthreads();

    float4v acc = {0.f, 0.f, 0.f, 0.f};
    const int m = lane & 15, oct = lane >> 4;
    const int arow = (tt * 16 + m) * ASTR + oct * 4;
    const int brow = (ft * 16 + m) * ASTR + oct * 4;

    for (int c = 0; c < 16; ++c) {
        if (c < 15) {
            xg = xg4[(c + 1) * 16 + skq];
            bg = wsrc[(c + 1) * 8 + wkq];
        }
        const int bb = (c & 1) * BUFSZ;
        #pragma unroll
        for (int ks = 0; ks < 2; ++ks) {
            const int ao = bb + arow + ks * 16;
            const int bo = bb + brow + ks * 16;
            short8v ah = *reinterpret_cast<const short8v*>(lds + OFF_AH + ao);
            short8v al = *reinterpret_cast<const short8v*>(lds + OFF_AL + ao);
            short8v bh = *reinterpret_cast<const short8v*>(lds + OFF_BH + bo);
            short8v bl = *reinterpret_cast<const short8v*>(lds + OFF_BL + bo);
            acc = __builtin_amdgcn_mfma_f32_16x16x32_bf16(ah, bh, acc, 0, 0, 0);
            acc = __builtin_amdgcn_mfma_f32_16x16x32_bf16(ah, bl, acc, 0, 0, 0);
            acc = __builtin_amdgcn_mfma_f32_16x16x32_bf16(al, bh, acc, 0, 0, 0);
        }
        if (c < 15) {
            const int wb = ((c + 1) & 1) * BUFSZ;
            cvt_write_a(lds, wb, stok, skq, xg, ssum, ssq);
            *reinterpret_cast<uint4*>(lds + wb + wdst) = bg;
        }
        __syncthreads();
    }

    // stats partials + logits to Sb
    lds[OFF_PH + stok * 17 + skq] = ssum;
    lds[OFF_PS + stok * 17 + skq] = ssq;
    {
        const int row0 = tt * 16 + oct * 4;
        const int col  = ft * 16 + m;
        #pragma unroll
        for (int r = 0; r < 4; ++r)
            lds[OFF_SB + (row0 + r) * SBSTR + col] = acc[r];
    }
    __syncthreads();

    if (tid < 64) {
        float s = 0.f, q = 0.f;
        #pragma unroll
        for (int i = 0; i < 16; ++i) {
            s += lds[OFF_PH + tid * 17 + i];
            q += lds[OFF_PS + tid * 17 + i];
        }
        lds[OFF_SB + tid * SBSTR + 50] = s;
        lds[OFF_SB + tid * SBSTR + 51] = q;
    }
    __syncthreads();

    // ---- epilogue: per-token softmax / sigmoid + writes --------------------
    if (tid < 256) {
        const int t  = tid & 63;
        const int q  = tid >> 6;
        const int tg = blockIdx.x * 64 + t;
        const float* St = lds + OFF_SB + t * SBSTR;

        const float tsum = St[50], tss = St[51];
        const float mu  = tsum * (1.f / D_MODEL);
        const float var = tss * (1.f / D_MODEL) - mu * mu;
        const float rs  = rsqrtf(var + LN_EPS);

        if (q == 0) {
            float lg[8];
            #pragma unroll
            for (int r = 0; r < 8; ++r)
                lg[r] = rs * (St[r] - mu * c1[r]) + c2[r];
            float mx = lg[0];
            #pragma unroll
            for (int r = 1; r < 8; ++r) mx = fmaxf(mx, lg[r]);
            float sm = 0.f;
            #pragma unroll
            for (int r = 0; r < 8; ++r) { lg[r] = expf(lg[r] - mx); sm += lg[r]; }
            float inv = 1.f / sm;
            float4* o = reinterpret_cast<float4*>(rw_o + (size_t)tg * 8);
            o[0] = make_float4(lg[0]*inv, lg[1]*inv, lg[2]*inv, lg[3]*inv);
            o[1] = make_float4(lg[4]*inv, lg[5]*inv, lg[6]*inv, lg[7]*inv);
        } else if (q == 1) {
            float lg[8];
            #pragma unroll
            for (int r = 0; r < 8; ++r)
                lg[r] = rs * (St[8 + r] - mu * c1[8 + r]) + c2[8 + r];
            float gl = rs * (St[16] - mu * c1[16]) + c2[16];
            float mx = lg[0];
            #pragma unroll
            for (int r = 1; r < 8; ++r) mx = fmaxf(mx, lg[r]);
            float sm = 0.f;
            #pragma unroll
            for (int r = 0; r < 8; ++r) { lg[r] = expf(lg[r] - mx); sm += lg[r]; }
            float inv = sigmoidf(gl) / sm;
            float4* o = reinterpret_cast<float4*>(us_o + (size_t)tg * 8);
            o[0] = make_float4(lg[0]*inv, lg[1]*inv, lg[2]*inv, lg[3]*inv);
            o[1] = make_float4(lg[4]*inv, lg[5]*inv, lg[6]*inv, lg[7]*inv);
        } else {
            const int f0 = 17 + (q - 2) * 16;
            float4* o = reinterpret_cast<float4*>(wv_o + (size_t)tg * 32 + (q - 2) * 16);
            #pragma unroll
            for (int jq = 0; jq < 4; ++jq) {
                float v0 = rs * (St[f0 + jq*4 + 0] - mu * c1[f0 + jq*4 + 0]) + c2[f0 + jq*4 + 0];
                float v1 = rs * (St[f0 + jq*4 + 1] - mu * c1[f0 + jq*4 + 1]) + c2[f0 + jq*4 + 1];
                float v2 = rs * (St[f0 + jq*4 + 2] - mu * c1[f0 + jq*4 + 2]) + c2[f0 + jq*4 + 2];
                float v3 = rs * (St[f0 + jq*4 + 3] - mu * c1[f0 + jq*4 + 3]) + c2[f0 + jq*4 + 3];
                o[jq] = make_float4(v0, v1, v2, v3);
            }
        }
    }
}

// ---------------------------------------------------------------------------
// Fused scan (chunk-compose + chain), one block per (b,r). 64 blocks x 1024.
// ---------------------------------------------------------------------------
__global__ __launch_bounds__(1024) void k_scan(
    const float* __restrict__ us, const float* __restrict__ wv,
    float* __restrict__ S0)
{
    __shared__ float S_us[L_SEQ];           // 8 KB
    __shared__ float lA[N_HALF];            // 0.5 KB
    __shared__ float lB[N_HALF * 32];       // 16 KB

    const int tid = threadIdx.x;
    const int b   = blockIdx.x >> 3;
    const int r   = blockIdx.x & 7;

    #pragma unroll
    for (int i = 0; i < 2; ++i) {
        const int t = i * 1024 + tid;
        S_us[t] = us[((size_t)(b * L_SEQ + t)) * 8 + r];
    }
    __syncthreads();

    const int k  = tid & 31;
    const int hb = (tid >> 5) * 4;
    #pragma unroll
    for (int j = 0; j < 4; ++j) {
        const int h  = hb + j;
        const int t0 = h * HSTEP;
        const float* wvp = wv + ((size_t)(b * L_SEQ + t0)) * 32 + k;

        float Aacc = 1.f, Bacc = 0.f;
        #pragma unroll
        for (int gq = 0; gq < 2; ++gq) {
            float wl[8], ul[8];
            #pragma unroll
            for (int e = 0; e < 8; ++e) {
                wl[e] = wvp[(gq * 8 + e) * 32];
                ul[e] = S_us[t0 + gq * 8 + e];
            }
            #pragma unroll
            for (int e = 0; e < 8; ++e) {
                float a = 1.f - ul[e];
                Aacc *= a;
                Bacc = fmaf(a, Bacc, ul[e] * wl[e]);
            }
        }
        lB[h * 32 + k] = Bacc;
        if (k == 0) lA[h] = Aacc;
    }
    __syncthreads();

    if (tid < 32) {
        float stv = 0.f;
        float* S0p = S0 + ((size_t)(b * 8 + r) * N_HALF) * 32 + tid;
        for (int h = 0; h < N_HALF; ++h) {
            S0p[h * 32] = stv;
            stv = fmaf(lA[h], stv, lB[h * 32 + tid]);
        }
    }
}

// ---------------------------------------------------------------------------
// Replay each 16-step half-chunk from its start state. 128 blocks x 256 thr.
// ---------------------------------------------------------------------------
__global__ __launch_bounds__(256) void k_replay2(
    const float* __restrict__ rw, const float* __restrict__ us,
    const float* __restrict__ wv, const float* __restrict__ S0,
    float* __restrict__ rvs)
{
    const int gid = blockIdx.x * 256 + threadIdx.x;   // 0..32767
    const int k   = gid & 31;
    const int hu  = gid >> 5;        // b*128 + ch2
    const int b   = hu >> 7;
    const int ch2 = hu & 127;

    float s[8];
    #pragma unroll
    for (int r = 0; r < 8; ++r)
        s[r] = S0[((size_t)((b * 8 + r) * N_HALF) + ch2) * 32 + k];

    const int t0 = b * L_SEQ + ch2 * HSTEP;
    const float* rwp = rw + (size_t)t0 * 8;
    const float* usp = us + (size_t)t0 * 8;
    const float* wvp = wv + (size_t)t0 * 32 + k;
    float*       rvp = rvs + (size_t)t0 * 32 + k;

    #pragma unroll
    for (int g4 = 0; g4 < 4; ++g4) {
        float4 r0[4], r1[4], u0[4], u1[4];
        float  wl[4];
        #pragma unroll
        for (int j = 0; j < 4; ++j) {
            const int t = g4 * 4 + j;
            r0[j] = reinterpret_cast<const float4*>(rwp + t * 8)[0];
            r1[j] = reinterpret_cast<const float4*>(rwp + t * 8)[1];
            u0[j] = reinterpret_cast<const float4*>(usp + t * 8)[0];
            u1[j] = reinterpret_cast<const float4*>(usp + t * 8)[1];
            wl[j] = wvp[t * 32];
        }
        #pragma unroll
        for (int j = 0; j < 4; ++j) {
            const int t = g4 * 4 + j;
            float rv = r0[j].x*s[0] + r0[j].y*s[1] + r0[j].z*s[2] + r0[j].w*s[3]
                     + r1[j].x*s[4] + r1[j].y*s[5] + r1[j].z*s[6] + r1[j].w*s[7];
            rvp[t * 32] = rv;
            const float w = wl[j];
            s[0] = fmaf(u0[j].x, w - s[0], s[0]);
            s[1] = fmaf(u0[j].y, w - s[1], s[1]);
            s[2] = fmaf(u0[j].z, w - s[2], s[2]);
            s[3] = fmaf(u0[j].w, w - s[3], s[3]);
            s[4] = fmaf(u1[j].x, w - s[4], s[4]);
            s[5] = fmaf(u1[j].y, w - s[5], s[5]);
            s[6] = fmaf(u1[j].z, w - s[6], s[6]);
            s[7] = fmaf(u1[j].w, w - s[7], s[7]);
        }
    }
}

// ---------------------------------------------------------------------------
// out[b,t,d] = mix * (sum_k rvs[b,t,k] * Wrp[d,k] + brp[d]).  v1 (measured-fast)
// ---------------------------------------------------------------------------
__global__ __launch_bounds__(256) void k_outproj(
    const float* __restrict__ rvs, const float* __restrict__ Wrp,
    const float* __restrict__ brp, const float* __restrict__ mix_p,
    float* __restrict__ out)
{
    const int d    = blockIdx.y * 256 + threadIdx.x;
    const int tok0 = blockIdx.x * 64;

    float4 wr[8];
    #pragma unroll
    for (int q = 0; q < 8; ++q)
        wr[q] = reinterpret_cast<const float4*>(Wrp)[(size_t)d * 8 + q];

    const float bias = brp[d];
    const float mix  = mix_p[0];

    for (int t = 0; t < 64; ++t) {
        const float4* rv = reinterpret_cast<const float4*>(rvs + (size_t)(tok0 + t) * 32);
        float acc = 0.f;
        #pragma unroll
        for (int q = 0; q < 8; ++q) {
            float4 v = rv[q];
            acc += wr[q].x*v.x + wr[q].y*v.y + wr[q].z*v.z + wr[q].w*v.w;
        }
        out[(size_t)(tok0 + t) * D_MODEL + d] = mix * (acc + bias);
    }
}

// ---------------------------------------------------------------------------
extern "C" void kernel_launch(void* const* d_in, const int* in_sizes, int n_in,
                              void* d_out, int out_size, void* d_ws, size_t ws_size,
                              hipStream_t stream)
{
    const float* x    = (const float*)d_in[0];
    const float* ln_w = (const float*)d_in[1];
    const float* ln_b = (const float*)d_in[2];
    const float* Wrq  = (const float*)d_in[3];
    const float* brq  = (const float*)d_in[4];
    const float* Wrp  = (const float*)d_in[5];
    const float* brp  = (const float*)d_in[6];
    const float* Wwq  = (const float*)d_in[7];
    const float* bwq  = (const float*)d_in[8];
    const float* Wwv  = (const float*)d_in[9];
    const float* bwv  = (const float*)d_in[10];
    const float* Wwg  = (const float*)d_in[11];
    const float* bwg  = (const float*)d_in[12];
    const float* mix  = (const float*)d_in[13];
    float* out = (float*)d_out;

    // workspace layout (floats)
    float* ws   = (float*)d_ws;
    float* rw_b = ws;                 // 16384*8      = 131072
    float* us_b = ws + 131072;        // 16384*8      = 131072
    float* wv_b = ws + 262144;        // 16384*32     = 524288
    float* S0_b = ws + 786432;        // 8*8*128*32   = 262144
    float* rv_b = ws + 1048576;       // 16384*32     = 524288
    // Wbh/Wbl/c1/c2 overlay rv_b: consumed by k_lnmfma before k_replay2 writes rv_b
    unsigned short* Wbh = (unsigned short*)rv_b;            // 64*1024 shorts
    unsigned short* Wbl = (unsigned short*)(rv_b + 32768);  // 64*1024 shorts
    float* c1_b = rv_b + 65536;       // 64
    float* c2_b = rv_b + 65600;       // 64

    k_prep2<<<64, 256, 0, stream>>>(ln_w, ln_b, Wrq, brq, Wwq, bwq,
                                    Wwv, bwv, Wwg, bwg, Wbh, Wbl, c1_b, c2_b);
    k_lnmfma<<<256, 1024, LDS_DW * 4, stream>>>(
        x, (const uint4*)Wbh, (const uint4*)Wbl, c1_b, c2_b, rw_b, us_b, wv_b);
    k_scan   <<<64, 1024, 0, stream>>>(us_b, wv_b, S0_b);
    k_replay2<<<128, 256, 0, stream>>>(rw_b, us_b, wv_b, S0_b, rv_b);
    dim3 gc(N_TOK / 64, 4);
    k_outproj<<<gc, 256, 0, stream>>>(rv_b, Wrp, brp, mix, out);
}